// Round 8
// baseline (183.880 us; speedup 1.0000x reference)
//
#include <hip/hip_runtime.h>
#include <hip/hip_bf16.h>

#define EPSV 1e-5f

typedef __attribute__((ext_vector_type(8))) short short8;
typedef __attribute__((ext_vector_type(4))) float f32x4;
typedef __attribute__((ext_vector_type(2))) float f32x2;
typedef __attribute__((ext_vector_type(4))) unsigned u32x4;

// ws layout: w2 (1,179,648 B) | st (2,048 B)
#define W2_BYTES 1179648ull

// w_deform (o, C_in, 3, 3) fp32 -> w2 bf16 [o][K], K = p*288 + k*32 + c,
// C_in = p*32 + c (p = phase 0..7).  Also zero st.
__global__ __launch_bounds__(256) void wt2_kernel(const float* __restrict__ wd,
                                                  __hip_bfloat16* __restrict__ w2,
                                                  float* __restrict__ st) {
  int idx = blockIdx.x * 256 + threadIdx.x;   // o*2304 + p*288 + k*32 + c
  int c  = idx & 31;
  int r  = idx >> 5;          // o*72 + p*9 + k
  int k  = r % 9;
  int r2 = r / 9;             // o*8 + p
  int p  = r2 & 7;
  int o  = r2 >> 3;
  w2[idx] = __float2bfloat16(wd[(o * 256 + p * 32 + c) * 9 + k]);
  if (blockIdx.x < 2) st[blockIdx.x * 256 + threadIdx.x] = 0.f;
}

static __device__ __forceinline__ f32x2 unpk(unsigned u) {
  union { unsigned i; float f; } lo, hi;
  lo.i = u << 16;
  hi.i = u & 0xffff0000u;
  return (f32x2){lo.f, hi.f};
}

static __device__ __forceinline__ unsigned pkbf(float a, float b) {
  __hip_bfloat162 p = __float22bfloat162_rn(make_float2(a, b));
  return *(unsigned*)&p;
}

// Fused sample+GEMM, ASYNC producer/consumer.  Corrected protocol (R8):
//  * flag adds lane0-only (per-thread atomicAdd coalesces to popcount! G12)
//  * x-window staging on a STATIC tile-indexed schedule with 10 producer-only
//    rendezvous at tiles {4,5,9,13,14,18,22,23,27,31}: each slab's commit
//    window sits strictly between the displaced slab's last read and the new
//    slab's first read, rendezvous-fenced on both sides (producer skew <= 4
//    tiles via the sB ring, so per-wave scheduling is NOT safe).
//  * every spin exit: asm ""::"memory" + sched_barrier(0) (no load hoisting);
//    every signal: lgkmcnt(0) first (no LDS op sinks past it).
// Flags: flg[0..3]=ready[slot], flg[4..7]=done[slot], flg[8]=rendezvous.
// Consumers (waves 0-3): 64M x 128N; spin ready>=4(pass+1) -> 16 ds_read +
//   64 MFMA -> lgkmcnt(0) -> done+=1.  A (L2-resident w2) global->reg.
// Producers (waves 4-7, setprio 1): spin done>=4*pass -> produce (16 gathers
//   + blend, 32ch/thread) -> commit x rows -> lgkmcnt(0) -> ready+=1.
__global__ __launch_bounds__(512, 2) void fused_kernel(
    const float* __restrict__ x, const float* __restrict__ shp,
    const float* __restrict__ woff, const __hip_bfloat16* __restrict__ w2,
    float* __restrict__ out, float* __restrict__ st) {
  __shared__ __align__(16) unsigned short sX[2][8 * 64 * 32];  // 2 x 32 KB x-window
  __shared__ __align__(16) unsigned short sB[4][128 * 64];     // 4 x 16 KB ring
  __shared__ float sW[288];
  __shared__ int flg[9];

  const int b    = blockIdx.x & 7;       // XCD swizzle: batch -> XCD
  const int band = blockIdx.x >> 3;      // 0..31
  const int h0   = band << 1;
  const int t    = threadIdx.x;
  const int wv   = t >> 6, lane = t & 63;
  const int quad = lane >> 4, l15 = lane & 15;

  const float* xb = x + ((size_t)b << 20);
  const unsigned short* w2b = (const unsigned short*)w2;

  if (t < 9) flg[t] = 0;
  __syncthreads();                       // flags visible; the ONLY full barrier

  if (wv < 4) {
    // ============================ CONSUMER ============================
    const int cw = wv;                       // M-stripe: rows cw*64..+63
    const unsigned short* aro =
        w2b + (size_t)((cw << 6) + l15) * 2304 + (quad << 3);

    f32x4 acc[4][8];
#pragma unroll
    for (int mo = 0; mo < 4; ++mo)
#pragma unroll
      for (int np = 0; np < 8; ++np) acc[mo][np] = (f32x4){0.f, 0.f, 0.f, 0.f};

    short8 afc[2][4];                        // A frags for tile j
#pragma unroll
    for (int ks = 0; ks < 2; ++ks)
#pragma unroll
      for (int mo = 0; mo < 4; ++mo)
        afc[ks][mo] = *(const short8*)(aro + (size_t)(mo << 4) * 2304 + (ks << 5));

    for (int j = 0; j < 36; ++j) {
      {  // wait: tile j fully produced (all 4 producer waves this pass)
        const int need = ((j >> 2) + 1) << 2;
        volatile int* fr = (volatile int*)&flg[j & 3];
        while (*fr < need) {}
      }
      asm volatile("" ::: "memory");         // no sB reads hoisted above spin
      __builtin_amdgcn_sched_barrier(0);
      const unsigned short* Bc = sB[j & 3];
#pragma unroll
      for (int np = 0; np < 8; ++np) {
        const int row = (np << 4) + l15;
#pragma unroll
        for (int ks = 0; ks < 2; ++ks) {
          short8 bf = *(const short8*)&Bc[(row << 6) +
                         ((((ks << 2) + quad) ^ (row & 7)) << 3)];
#pragma unroll
          for (int mo = 0; mo < 4; ++mo)
            acc[mo][np] = __builtin_amdgcn_mfma_f32_16x16x32_bf16(afc[ks][mo], bf, acc[mo][np], 0, 0, 0);
        }
      }
      if (j < 35) {
#pragma unroll
        for (int ks = 0; ks < 2; ++ks)
#pragma unroll
          for (int mo = 0; mo < 4; ++mo)
            afc[ks][mo] = *(const short8*)(aro + (size_t)(mo << 4) * 2304 +
                                           (size_t)((j + 1) << 6) + (ks << 5));
      }
      asm volatile("s_waitcnt lgkmcnt(0)" ::: "memory");  // sB reads retired
      if (lane == 0) atomicAdd(&flg[4 + (j & 3)], 1);     // slot free (this wave)
    }

    // GN partial stats (group = 8 consecutive o)
#pragma unroll
    for (int mo = 0; mo < 4; ++mo) {
      float s = 0.f, q = 0.f;
#pragma unroll
      for (int np = 0; np < 8; ++np)
#pragma unroll
        for (int r = 0; r < 4; ++r) { float v = acc[mo][np][r]; s += v; q += v * v; }
#pragma unroll
      for (int m = 1; m < 16; m <<= 1) { s += __shfl_xor(s, m, 64); q += __shfl_xor(q, m, 64); }
      if (l15 == 0) {
        int gid = (b << 5) + (cw << 3) + (mo << 1) + (quad >> 1);
        atomicAdd(&st[gid], s);
        atomicAdd(&st[256 + gid], q);
      }
    }

    // C store: col(n)=l15, row(o)=quad*4+r per 16x16 block
    float* ob = out + (((size_t)((b << 8) + (cw << 6))) << 12) + (band << 7);
#pragma unroll
    for (int mo = 0; mo < 4; ++mo)
#pragma unroll
      for (int np = 0; np < 8; ++np)
#pragma unroll
        for (int r = 0; r < 4; ++r)
          ob[((size_t)((mo << 4) + (quad << 2) + r) << 12) + (np << 4) + l15] = acc[mo][np][r];
  } else {
    // ============================ PRODUCER ============================
    __builtin_amdgcn_s_setprio(1);           // producer = rate-limiting role
    const int pid     = t - 256;             // 0..255
    const int pxn     = pid & 127;           // band-local pixel n = hh*64+pxl
    const int tapslot = pid >> 7;            // 0/1 (wave-uniform)
    const int pxl     = pxn & 63;
    const int h       = h0 + (pxn >> 6);
    const int spx     = pid & 63;            // x-stage: pixel
    const int sc8     = (pid >> 6) & 3;      // x-stage: 8-ch slot
    const int wslot   = (sc8 ^ ((spx >> 1) & 3)) << 3;

    for (int i = pid; i < 288; i += 256) sW[i] = woff[i];

    float a0 = shp[((size_t)(b * 4 + 0) << 12) + (h << 6) + pxl];
    float a1 = shp[((size_t)(b * 4 + 1) << 12) + (h << 6) + pxl];
    float a2 = shp[((size_t)(b * 4 + 2) << 12) + (h << 6) + pxl];
    float a3 = shp[((size_t)(b * 4 + 3) << 12) + (h << 6) + pxl];

    // ---- prologue: stage sX[0] (slab 0, rows h0-3..h0+4 clamped) ----
    {
      const float* xph = xb + ((size_t)(sc8 << 3) << 12) + spx;
#pragma unroll
      for (int j = 0; j < 8; ++j) {
        const int grow = min(max(h0 - 3 + j, 0), 63);
        float v[8];
#pragma unroll
        for (int jj = 0; jj < 8; ++jj) v[jj] = xph[(jj << 12) + (grow << 6)];
        *(u32x4*)&sX[0][((((j << 6) + spx) << 5)) + wslot] =
            (u32x4){pkbf(v[0], v[1]), pkbf(v[2], v[3]), pkbf(v[4], v[5]), pkbf(v[6], v[7])};
      }
    }
    asm volatile("s_waitcnt lgkmcnt(0)" ::: "memory");  // slab0 + sW committed
    if (lane == 0) atomicAdd(&flg[8], 1);
    { volatile int* fp = (volatile int*)&flg[8]; while (*fp < 4) {} }
    asm volatile("" ::: "memory");
    __builtin_amdgcn_sched_barrier(0);

    // sample tap (wave-uniform) for pixel (h,pxl), 32 ch -> sB[slot]
    auto produce = [&](int tap, int slot) {
      const int ph = tap / 9;
      const int tk = tap - ph * 9;
      const int kr = tk / 3, kc = tk - kr * 3;
      const float* wp = &sW[(((ph >> 1) * 9 + tk)) << 3];
      float dy = wp[0]*a0 + wp[1]*a1 + wp[2]*a2 + wp[3]*a3;
      float dx = wp[4]*a0 + wp[5]*a1 + wp[6]*a2 + wp[7]*a3;
      float py  = dy + (float)(h + kr - 1);
      float pxp = dx + (float)(pxl + kc - 1);
      float y0f = floorf(py), x0f = floorf(pxp);
      float ly = py - y0f, lx = pxp - x0f;
      int y0 = (int)y0f, x0 = (int)x0f;
      float m_y0 = (y0 >=  0 && y0 <= 63) ? 1.f : 0.f;
      float m_y1 = (y0 >= -1 && y0 <= 62) ? 1.f : 0.f;
      float m_x0 = (x0 >=  0 && x0 <= 63) ? 1.f : 0.f;
      float m_x1 = (x0 >= -1 && x0 <= 62) ? 1.f : 0.f;
      float w00 = (1.f - ly) * (1.f - lx) * m_y0 * m_x0;
      float w01 = (1.f - ly) * lx         * m_y0 * m_x1;
      float w10 = ly         * (1.f - lx) * m_y1 * m_x0;
      float w11 = ly         * lx         * m_y1 * m_x1;
      int yc0 = min(max(y0, 0), 63),     yc1 = min(max(y0 + 1, 0), 63);
      int xc0 = min(max(x0, 0), 63),     xc1 = min(max(x0 + 1, 0), 63);
      int ry0 = min(max(yc0 - (h0 - 3), 0), 7);
      int ry1 = min(max(yc1 - (h0 - 3), 0), 7);
      const unsigned short* Xc = sX[ph & 1];
      const int z0 = (xc0 >> 1) & 3, z1 = (xc1 >> 1) & 3;
      const int e00 = ((ry0 << 6) + xc0) << 5, e01 = ((ry0 << 6) + xc1) << 5;
      const int e10 = ((ry1 << 6) + xc0) << 5, e11 = ((ry1 << 6) + xc1) << 5;
      uint4 Av[4], Bv[4], Cv[4], Dv[4];
#pragma unroll
      for (int j = 0; j < 4; ++j) {
        Av[j] = *(const uint4*)&Xc[e00 + ((j ^ z0) << 3)];
        Bv[j] = *(const uint4*)&Xc[e01 + ((j ^ z1) << 3)];
        Cv[j] = *(const uint4*)&Xc[e10 + ((j ^ z0) << 3)];
        Dv[j] = *(const uint4*)&Xc[e11 + ((j ^ z1) << 3)];
      }
#pragma unroll
      for (int j = 0; j < 4; ++j) {
        unsigned ua[4] = {Av[j].x, Av[j].y, Av[j].z, Av[j].w};
        unsigned ub[4] = {Bv[j].x, Bv[j].y, Bv[j].z, Bv[j].w};
        unsigned uc[4] = {Cv[j].x, Cv[j].y, Cv[j].z, Cv[j].w};
        unsigned ud[4] = {Dv[j].x, Dv[j].y, Dv[j].z, Dv[j].w};
        unsigned ov[4];
#pragma unroll
        for (int q = 0; q < 4; ++q) {
          f32x2 v = unpk(ua[q]) * w00 + unpk(ub[q]) * w01
                  + unpk(uc[q]) * w10 + unpk(ud[q]) * w11;
          ov[q] = pkbf(v.x, v.y);
        }
        *(u32x4*)&sB[slot][(pxn << 6) + ((((tapslot << 2) + j) ^ (pxn & 7)) << 3)] =
            (u32x4){ov[0], ov[1], ov[2], ov[3]};
      }
    };

    int rdvK = 1;
    for (int j = 0; j < 36; ++j) {
      // ---- producer rendezvous (slab hand-off safety; see header) ----
      if (j == 4 || j == 5 || j == 9 || j == 13 || j == 14 ||
          j == 18 || j == 22 || j == 23 || j == 27 || j == 31) {
        asm volatile("s_waitcnt lgkmcnt(0)" ::: "memory");
        if (lane == 0) atomicAdd(&flg[8], 1);
        ++rdvK;
        const int needR = rdvK << 2;
        volatile int* fp = (volatile int*)&flg[8];
        while (*fp < needR) {}
        asm volatile("" ::: "memory");
        __builtin_amdgcn_sched_barrier(0);
      }
      // ---- static stage map: slab s, rows 2m..2m+1 this tile ----
      // windows: s1:[0,3] s2:[5,8] s3:[9,12] s4:[14,17] s5:[18,21]
      //          s6:[23,26] s7:[27,30]  (fit between old-slab-last-read and
      //          new-slab-first-read, rendezvous-fenced)
      int s = 0, m = 0;
      if (j <= 3)                  { s = 1;                  m = j; }
      else if (j >= 5 && j <= 12)  { s = 2 + ((j - 5) >> 2);  m = (j - 5) & 3; }
      else if (j >= 14 && j <= 21) { s = 4 + ((j - 14) >> 2); m = (j - 14) & 3; }
      else if (j >= 23 && j <= 30) { s = 6 + ((j - 23) >> 2); m = (j - 23) & 3; }
      float xrA[8], xrB[8];
      if (s) {                               // issue early (hide under produce)
        const float* xph = xb + ((size_t)((s << 5) + (sc8 << 3)) << 12) + spx;
        const int g0 = min(max(h0 - 3 + (m << 1), 0), 63);
        const int g1 = min(max(h0 - 2 + (m << 1), 0), 63);
#pragma unroll
        for (int jj = 0; jj < 8; ++jj) xrA[jj] = xph[(jj << 12) + (g0 << 6)];
#pragma unroll
        for (int jj = 0; jj < 8; ++jj) xrB[jj] = xph[(jj << 12) + (g1 << 6)];
      }
      {  // ring wait: slot freed (tile j-4 consumed by all 4 consumer waves)
        const int need = (j >> 2) << 2;
        volatile int* fd = (volatile int*)&flg[4 + (j & 3)];
        while (*fd < need) {}
      }
      asm volatile("" ::: "memory");
      __builtin_amdgcn_sched_barrier(0);
      produce((j << 1) + tapslot, j & 3);
      if (s) {                               // commit late (loads drained)
        *(u32x4*)&sX[s & 1][((((m << 1) << 6) + spx) << 5) + wslot] =
            (u32x4){pkbf(xrA[0], xrA[1]), pkbf(xrA[2], xrA[3]),
                    pkbf(xrA[4], xrA[5]), pkbf(xrA[6], xrA[7])};
        *(u32x4*)&sX[s & 1][(((((m << 1) + 1) << 6) + spx) << 5) + wslot] =
            (u32x4){pkbf(xrB[0], xrB[1]), pkbf(xrB[2], xrB[3]),
                    pkbf(xrB[4], xrB[5]), pkbf(xrB[6], xrB[7])};
      }
      asm volatile("s_waitcnt lgkmcnt(0)" ::: "memory");  // sB+sX writes done
      if (lane == 0) atomicAdd(&flg[j & 3], 1);           // tile j: wave done
    }
  }
}

// Normalize + affine + ReLU from atomic sums (full-line nt store).
__global__ __launch_bounds__(256) void norm_kernel(float* __restrict__ o,
    const float* __restrict__ st, const float* __restrict__ gamma,
    const float* __restrict__ beta) {
  int idx = blockIdx.x * 256 + threadIdx.x;    // float4s: 2,097,152
  f32x4* p = (f32x4*)o;
  int c = (idx >> 10) & 255;
  int b = idx >> 18;
  int g = b * 32 + (c >> 3);
  const float invn = 1.f / 32768.f;
  float mu  = st[g] * invn;
  float var = st[256 + g] * invn - mu * mu;
  float ga = gamma[c] * rsqrtf(var + EPSV);
  float be = beta[c] - mu * ga;
  f32x4 v = p[idx];
  v.x = fmaxf(fmaf(v.x, ga, be), 0.f);
  v.y = fmaxf(fmaf(v.y, ga, be), 0.f);
  v.z = fmaxf(fmaf(v.z, ga, be), 0.f);
  v.w = fmaxf(fmaf(v.w, ga, be), 0.f);
  __builtin_nontemporal_store(v, &p[idx]);
}

extern "C" void kernel_launch(void* const* d_in, const int* in_sizes, int n_in,
                              void* d_out, int out_size, void* d_ws, size_t ws_size,
                              hipStream_t stream) {
  const float* x     = (const float*)d_in[0];
  const float* shp   = (const float*)d_in[1];
  const float* woff  = (const float*)d_in[2];
  const float* wdef  = (const float*)d_in[3];
  const float* gamma = (const float*)d_in[4];
  const float* beta  = (const float*)d_in[5];
  float* out = (float*)d_out;
  __hip_bfloat16* w2 = (__hip_bfloat16*)d_ws;
  float* st          = (float*)((char*)d_ws + W2_BYTES);

  hipLaunchKernelGGL(wt2_kernel,   dim3(2304), dim3(256), 0, stream, wdef, w2, st);
  hipLaunchKernelGGL(fused_kernel, dim3(256),  dim3(512), 0, stream, x, shp, woff, w2, out, st);
  hipLaunchKernelGGL(norm_kernel,  dim3(8192), dim3(256), 0, stream, out, st, gamma, beta);
}